// Round 16
// baseline (38.732 us; speedup 1.0000x reference)
//
#include <hip/hip_runtime.h>
#include <hip/hip_fp16.h>

#define N_ROWS 1024
#define DIM 256
#define HID 512
#define CTR 16          // uints per counter (64B stride)

typedef _Float16 half_t;
typedef __attribute__((ext_vector_type(4))) _Float16 half4v;
typedef __attribute__((ext_vector_type(8))) _Float16 half8v;
typedef __attribute__((ext_vector_type(16))) float f32x16;

struct Params {
    const float* a;
    const float* b;
    const float* w[6];      // fp32 K x N
    const float* bias[6];
    unsigned* c1;           // 64 counters (net*32+g), target 4
    unsigned* c3;           // 32 counters (g), target 8
    float* acc;
    unsigned* done;         // target 128
    float* zbase;           // zero region (counters+acc+done)
    float* part_s;          // [16][256] colstats partials
    float* part_s2;         // [16][256]
    float* g_part;          // [2][4][1024][256] f32 L2 partials
    half_t* g_h1[2];        // [1024][512] f16
    half_t* wt[6];          // fragment-packed f16 weights
    float* out;
};

// ---------------- prep: pack W + colstats partials + zero counters ----------------
__global__ __launch_bounds__(256) void prep_kernel(Params p) {
    const int y = blockIdx.y, bx = blockIdx.x, tid = threadIdx.x;

    if (y == 6) {
        if (bx < 16) {          // colstats partials: 16 blocks x 64 rows, plain stores
            const int d = tid, r0 = bx * 64;
            float s = 0.f, s2 = 0.f;
            #pragma unroll 8
            for (int r = 0; r < 64; ++r) {
                float v = p.b[(r0 + r) * DIM + d];
                s += v; s2 = fmaf(v, v, s2);
            }
            p.part_s[bx * 256 + d] = s;
            p.part_s2[bx * 256 + d] = s2;
        } else if (bx == 16) {  // zero counters + acc + done (2048 floats)
            #pragma unroll
            for (int k = 0; k < 8; ++k) p.zbase[tid + k * 256] = 0.f;
        }
        return;
    }
    __shared__ float T[32][33];
    const float* src = p.w[y];
    half_t* dst = p.wt[y];
    const int K = (y < 2) ? DIM : HID;
    const int N = (y < 4) ? HID : DIM;
    const int C = K >> 5;
    const int tilesN = N >> 5;
    if (bx >= C * tilesN) return;
    const int tk = bx / tilesN, tn = bx % tilesN;

    {
        const int r = tid >> 3, c4 = (tid & 7) * 4;
        float4 v = *(const float4*)&src[(tk * 32 + r) * N + tn * 32 + c4];
        T[r][c4 + 0] = v.x; T[r][c4 + 1] = v.y; T[r][c4 + 2] = v.z; T[r][c4 + 3] = v.w;
    }
    __syncthreads();
    const int which = tid >> 7;
    const int lane64 = (tid >> 1) & 63;
    const int epart = tid & 1;
    const int hi = lane64 >> 5, lr = lane64 & 31;
    const int rbase = which * 16 + hi * 8 + epart * 4;
    half4v h;
    h[0] = (half_t)T[rbase + 0][lr];
    h[1] = (half_t)T[rbase + 1][lr];
    h[2] = (half_t)T[rbase + 2][lr];
    h[3] = (half_t)T[rbase + 3][lr];
    *(half4v*)&dst[((tn * C + tk) * 2 + which) * 512 + lane64 * 8 + epart * 4] = h;
}

// ---------------- flag sync (r6-r15 proven) ----------------
__device__ __forceinline__ void flag_add(unsigned* c) {
    asm volatile("s_waitcnt vmcnt(0)" ::: "memory");
    __syncthreads();
    if (threadIdx.x == 0)
        __hip_atomic_fetch_add(c, 1u, __ATOMIC_RELAXED, __HIP_MEMORY_SCOPE_AGENT);
}
__device__ __forceinline__ void flag_wait(unsigned* c, unsigned tgt) {
    if (threadIdx.x == 0) {
        while (__hip_atomic_load(c, __ATOMIC_RELAXED, __HIP_MEMORY_SCOPE_AGENT) < tgt)
            __builtin_amdgcn_s_sleep(1);
    }
    __syncthreads();
    asm volatile("" ::: "memory");
}

// ---------------- wave MFMA over KC chunks: A from LDS [.][32][40], W packed ----
template <int KC>
__device__ __forceinline__ f32x16 mma_ab(const half_t* __restrict__ Ap0,
                                         const half_t* __restrict__ Wp,
                                         const int lane) {
    const int lr = lane & 31, hi = lane >> 5;
    const int sa = (lr >> 3) & 3;
    const int aoff0 = lr * 40 + ((hi ^ sa) * 8);
    const int aoff1 = lr * 40 + (((hi + 2) ^ sa) * 8);
    f32x16 acc;
    #pragma unroll
    for (int i = 0; i < 16; ++i) acc[i] = 0.f;
    #pragma unroll
    for (int c = 0; c < KC; ++c) {
        half8v av0 = *(const half8v*)(Ap0 + c * 1280 + aoff0);
        half8v av1 = *(const half8v*)(Ap0 + c * 1280 + aoff1);
        half8v bv0 = *(const half8v*)(Wp + c * 1024);
        half8v bv1 = *(const half8v*)(Wp + c * 1024 + 512);
        acc = __builtin_amdgcn_mfma_f32_32x32x16_f16(av0, bv0, acc, 0, 0, 0);
        acc = __builtin_amdgcn_mfma_f32_32x32x16_f16(av1, bv1, acc, 0, 0, 0);
    }
    return acc;
}

// ---------------- stage helpers (r13 proven) ----------------
__device__ __forceinline__ void stage_a(const float* __restrict__ a, half_t* XA,
                                        const int R0, const int tid) {
    const int r = tid >> 4, q = tid & 15;
    const float* src = &a[(R0 + r) * DIM + q * 16];
    float4 v0 = *(const float4*)(src);
    float4 v1 = *(const float4*)(src + 4);
    float4 v2 = *(const float4*)(src + 8);
    float4 v3 = *(const float4*)(src + 12);
    half8v h0, h1;
    h0[0] = (half_t)v0.x; h0[1] = (half_t)v0.y; h0[2] = (half_t)v0.z; h0[3] = (half_t)v0.w;
    h0[4] = (half_t)v1.x; h0[5] = (half_t)v1.y; h0[6] = (half_t)v1.z; h0[7] = (half_t)v1.w;
    h1[0] = (half_t)v2.x; h1[1] = (half_t)v2.y; h1[2] = (half_t)v2.z; h1[3] = (half_t)v2.w;
    h1[4] = (half_t)v3.x; h1[5] = (half_t)v3.y; h1[6] = (half_t)v3.z; h1[7] = (half_t)v3.w;
    const int c = q >> 1, kb0 = (q & 1) * 2, sr = (r >> 3) & 3;
    *(half8v*)&XA[c * 1280 + r * 40 + ((kb0 ^ sr) * 8)] = h0;
    *(half8v*)&XA[c * 1280 + r * 40 + (((kb0 + 1) ^ sr) * 8)] = h1;
}

__device__ __forceinline__ void stage_h(const half_t* __restrict__ src, half_t* XA,
                                        const int R0, const int tid) {
    const int r = tid >> 4, q = tid & 15;
    const half_t* sp = &src[(R0 + r) * HID + q * 32];
    half8v x0 = *(const half8v*)(sp);
    half8v x1 = *(const half8v*)(sp + 8);
    half8v x2 = *(const half8v*)(sp + 16);
    half8v x3 = *(const half8v*)(sp + 24);
    const int sr = (r >> 3) & 3;
    half_t* d = &XA[q * 1280 + r * 40];
    *(half8v*)&d[(0 ^ sr) * 8] = x0;
    *(half8v*)&d[(1 ^ sr) * 8] = x1;
    *(half8v*)&d[(2 ^ sr) * 8] = x2;
    *(half8v*)&d[(3 ^ sr) * 8] = x3;
}

// LDS offsets
#define OFF_H2C   40960
#define OFF_REDH  51200
#define OFF_BSUM  59904

// ---------------- L0/L1 reduce (2-way k-split, 128-col slice) ----------------
// TO_LDS=0: wide agent stores to dstG. TO_LDS=1: restage into H2C (swizzled).
template <int TO_LDS>
__device__ __forceinline__ void reduce2x(f32x16 acc, char* smem, int tl, int kh,
                                         int lane, int tid,
                                         const float* __restrict__ bias, int colbase,
                                         unsigned short* __restrict__ dstG,
                                         int R0) {
    float* redf = (float*)smem;
    half_t* redh = (half_t*)(smem + OFF_REDH);
    __syncthreads();                    // XA reads complete
    if (kh) {
        #pragma unroll
        for (int i = 0; i < 16; ++i) redf[tl * 1024 + i * 64 + lane] = acc[i];
    }
    __syncthreads();
    if (!kh) {
        const int lr = lane & 31, hi = lane >> 5;
        const int coll = tl * 32 + lr;
        const float bv = bias[colbase + coll];
        #pragma unroll
        for (int i = 0; i < 16; ++i) {
            float v = acc[i] + redf[tl * 1024 + i * 64 + lane] + bv;
            v = fmaxf(v, 0.f);
            const int row = (i & 3) + 8 * (i >> 2) + 4 * hi;
            redh[row * 136 + coll] = (half_t)v;
        }
    }
    __syncthreads();
    if (TO_LDS) {
        half_t* H2C = (half_t*)(smem + OFF_H2C);
        const int row = tid >> 4, c8 = (tid & 15) * 8;
        half8v v = *(const half8v*)&redh[row * 136 + c8];
        const int ch = c8 >> 5, kb = (c8 & 31) >> 3, sr = (row >> 3) & 3;
        *(half8v*)&H2C[ch * 1280 + row * 40 + ((kb ^ sr) * 8)] = v;
        __syncthreads();
    } else {
        const int row = tid >> 4, c8 = (tid & 15) * 8;
        const unsigned long long* sp = (const unsigned long long*)&redh[row * 136 + c8];
        unsigned long long v0 = sp[0], v1 = sp[1];
        unsigned long long* dp = (unsigned long long*)&dstG[(R0 + row) * HID + colbase + c8];
        __hip_atomic_store(dp, v0, __ATOMIC_RELAXED, __HIP_MEMORY_SCOPE_AGENT);
        __hip_atomic_store(dp + 1, v1, __ATOMIC_RELAXED, __HIP_MEMORY_SCOPE_AGENT);
    }
}

// ---------------- main: 256 blocks = 2 nets x 32 rowgroups x 4 col-slices ----
__global__ void __launch_bounds__(512, 2) main_kernel(Params p) {
    __shared__ alignas(16) char smem[59968];
    half_t* XA = (half_t*)smem;                 // [16][32][40] f16 (40960 B)
    half_t* H2C = (half_t*)(smem + OFF_H2C);    // [4][32][40] f16 (10240 B)
    float* bsum = (float*)(smem + OFF_BSUM);

    const int bid = blockIdx.x, tid = threadIdx.x;
    const int net = bid & 1, g = (bid >> 1) & 31, s = bid >> 6;
    const int R0 = g * 32;
    const int w = tid >> 6, lane = tid & 63;

    // ---- L0: a @ w[net], cols [s*128,+128) -> g_h1 ----
    stage_a(p.a, XA, R0, tid);
    __syncthreads();
    {
        const int tl = w >> 1, kh = w & 1;
        f32x16 acc = mma_ab<4>(XA + kh * 4 * 1280,
                               p.wt[net] + ((s * 4 + tl) * 8 + kh * 4) * 1024 + lane * 8,
                               lane);
        reduce2x<0>(acc, smem, tl, kh, lane, tid, p.bias[net], s * 128,
                    (unsigned short*)p.g_h1[net], R0);
    }
    flag_add(p.c1 + (net * 32 + g) * CTR);

    // ---- L1: h1 @ w[2+net], cols [s*128,+128) -> H2C (LDS only, no sync) ----
    flag_wait(p.c1 + (net * 32 + g) * CTR, 4);
    stage_h(p.g_h1[net], XA, R0, tid);
    __syncthreads();
    {
        const int tl = w >> 1, kh = w & 1;
        f32x16 acc = mma_ab<8>(XA + kh * 8 * 1280,
                               p.wt[2 + net] + ((s * 4 + tl) * 16 + kh * 8) * 1024 + lane * 8,
                               lane);
        reduce2x<1>(acc, smem, tl, kh, lane, tid, p.bias[2 + net], s * 128,
                    nullptr, R0);
    }

    // ---- L2 partial: own h2 slice (k = [s*128,+128)) @ w[4+net] -> g_part ----
    {
        f32x16 acc = mma_ab<4>(H2C,
                               p.wt[4 + net] + (w * 16 + s * 4) * 1024 + lane * 8,
                               lane);
        float* redf = (float*)smem;         // overlaps XA (dead)
        #pragma unroll
        for (int i = 0; i < 16; ++i) redf[w * 1024 + i * 64 + lane] = acc[i];
        __syncthreads();
        const int row = tid >> 4, c16 = (tid & 15) * 16;
        const int i0 = (row & 3) | ((row >> 3) << 2);
        const int hi2 = (row >> 2) & 1;
        float* dst = p.g_part + (((net * 4 + s) * 1024) + R0 + row) * 256 + c16;
        #pragma unroll
        for (int jj = 0; jj < 8; ++jj) {
            const int col0 = c16 + jj * 2;
            union { float f2[2]; unsigned long long u; } cv;
            #pragma unroll
            for (int e = 0; e < 2; ++e) {
                const int col = col0 + e;
                float v = redf[(col >> 5) * 1024 + i0 * 64 + (col & 31) + 32 * hi2];
                if (s == 0) v += p.bias[4 + net][col];
                cv.f2[e] = v;
            }
            __hip_atomic_store((unsigned long long*)dst + jj, cv.u,
                               __ATOMIC_RELAXED, __HIP_MEMORY_SCOPE_AGENT);
        }
    }
    flag_add(p.c3 + g * CTR);

    if (net == 0) return;

    // ---- loss (net==1): 128 blocks x 8 rows; wave w = one row ----
    if (tid == 0) *bsum = 0.f;
    const int d0 = lane * 4;
    float eb[4] = {0.f, 0.f, 0.f, 0.f}, eb2[4] = {0.f, 0.f, 0.f, 0.f};
    #pragma unroll
    for (int j = 0; j < 16; ++j) {          // colstats partial sum (poll shadow)
        float4 a4 = *(const float4*)&p.part_s[j * 256 + d0];
        float4 b4 = *(const float4*)&p.part_s2[j * 256 + d0];
        eb[0] += a4.x; eb[1] += a4.y; eb[2] += a4.z; eb[3] += a4.w;
        eb2[0] += b4.x; eb2[1] += b4.y; eb2[2] += b4.z; eb2[3] += b4.w;
    }
    const float invN = 1.0f / (float)N_ROWS;
    #pragma unroll
    for (int t = 0; t < 4; ++t) { eb[t] *= invN; eb2[t] *= invN; }

    flag_wait(p.c3 + g * CTR, 8);

    const int row = R0 + s * 8 + w;
    float m4[4] = {0.f, 0.f, 0.f, 0.f}, l4[4] = {0.f, 0.f, 0.f, 0.f};
    #pragma unroll
    for (int s4 = 0; s4 < 4; ++s4) {
        float4 mp = *(const float4*)&p.g_part[((s4) * 1024 + row) * 256 + d0];
        float4 lp = *(const float4*)&p.g_part[((4 + s4) * 1024 + row) * 256 + d0];
        m4[0] += mp.x; m4[1] += mp.y; m4[2] += mp.z; m4[3] += mp.w;
        l4[0] += lp.x; l4[1] += lp.y; l4[2] += lp.z; l4[3] += lp.w;
    }

    float ss = 0.f;
    #pragma unroll
    for (int t = 0; t < 4; ++t) ss = fmaf(m4[t], m4[t], ss);
    #pragma unroll
    for (int o = 32; o > 0; o >>= 1) ss += __shfl_xor(ss, o, 64);
    const float inv_norm = 1.f / fmaxf(sqrtf(ss), 1e-12f);

    float wacc = 0.f;
    #pragma unroll
    for (int t = 0; t < 4; ++t) {
        float mu = m4[t] * inv_norm;
        float lv = tanhf(l4[t]);
        float iv = expf(-lv);
        float diff2 = fmaf(mu, mu, fmaf(-2.f * mu, eb[t], eb2[t]));
        wacc += fmaf(diff2, iv, lv);
    }
    #pragma unroll
    for (int o = 32; o > 0; o >>= 1) wacc += __shfl_xor(wacc, o, 64);
    if (lane == 0) atomicAdd(bsum, wacc);
    __syncthreads();
    if (tid == 0) {
        atomicAdd(p.acc, *bsum);
        asm volatile("s_waitcnt vmcnt(0)" ::: "memory");
        unsigned prev = __hip_atomic_fetch_add(p.done, 1u, __ATOMIC_RELAXED,
                                               __HIP_MEMORY_SCOPE_AGENT);
        if (prev == 127u) {
            float v = __hip_atomic_load(p.acc, __ATOMIC_RELAXED, __HIP_MEMORY_SCOPE_AGENT);
            p.out[0] = v * (1.0f / (float)N_ROWS);
        }
    }
}

extern "C" void kernel_launch(void* const* d_in, const int* in_sizes, int n_in,
                              void* d_out, int out_size, void* d_ws, size_t ws_size,
                              hipStream_t stream) {
    Params p;
    p.a = (const float*)d_in[0];
    p.b = (const float*)d_in[1];
    p.w[0] = (const float*)d_in[2];  p.bias[0] = (const float*)d_in[3];   // mu L0
    p.w[2] = (const float*)d_in[4];  p.bias[2] = (const float*)d_in[5];   // mu L1
    p.w[4] = (const float*)d_in[6];  p.bias[4] = (const float*)d_in[7];   // mu L2
    p.w[1] = (const float*)d_in[8];  p.bias[1] = (const float*)d_in[9];   // lv L0
    p.w[3] = (const float*)d_in[10]; p.bias[3] = (const float*)d_in[11];  // lv L1
    p.w[5] = (const float*)d_in[12]; p.bias[5] = (const float*)d_in[13];  // lv L2

    float* f = (float*)d_ws;
    p.c1    = (unsigned*)f;                 // 64 x CTR = [0..1023]
    p.c3    = (unsigned*)(f + 1024);        // 32 x CTR = [1024..1535]
    p.acc   = f + 1536;
    p.done  = (unsigned*)(f + 1552);
    p.zbase = f;                            // zero f[0..2047] in prep
    p.part_s  = f + 4096;                   // [16][256]
    p.part_s2 = f + 8192;                   // [16][256]
    p.g_part  = f + 16384;                  // [2][4][1024][256] f32
    half_t* hb = (half_t*)(f + 16384 + 2 * 4 * 1024 * 256);
    p.g_h1[0] = hb;  hb += N_ROWS * HID;
    p.g_h1[1] = hb;  hb += N_ROWS * HID;
    p.wt[0] = hb;  hb += HID * DIM;
    p.wt[1] = hb;  hb += HID * DIM;
    p.wt[2] = hb;  hb += HID * HID;
    p.wt[3] = hb;  hb += HID * HID;
    p.wt[4] = hb;  hb += DIM * HID;
    p.wt[5] = hb;  hb += DIM * HID;
    p.out = (float*)d_out;

    prep_kernel<<<dim3(256, 7), 256, 0, stream>>>(p);
    main_kernel<<<256, 512, 0, stream>>>(p);
}

// Round 17
// 29.635 us; speedup vs baseline: 1.3070x; 1.3070x over previous
//
#include <hip/hip_runtime.h>
#include <hip/hip_fp16.h>

#define N_ROWS 1024
#define DIM 256
#define HID 512
#define CTR 16          // uints per counter (64B stride)

typedef _Float16 half_t;
typedef __attribute__((ext_vector_type(4))) _Float16 half4v;
typedef __attribute__((ext_vector_type(8))) _Float16 half8v;
typedef __attribute__((ext_vector_type(16))) float f32x16;

struct Params {
    const float* a;
    const float* b;
    const float* w[6];      // fp32 K x N
    const float* bias[6];
    unsigned* c1;           // 64 counters (net*32+g), target 32 (wave-level)
    unsigned* c2;           // 64 counters, target 32
    unsigned* c3;           // 32 counters (g), target 64
    float* acc;
    unsigned* done;         // target 128 (block-level)
    float* zbase;
    float* part_s;          // [64][256] colstats partials
    float* part_s2;         // [64][256]
    unsigned short* g_mu;   // [1024][256] f16
    unsigned short* g_lv;   // [1024][256] f16
    half_t* g_h1[2];        // [1024][512] f16
    half_t* g_h2[2];        // [1024][512] f16
    half_t* wt[6];          // fragment-packed f16 weights
    float* out;
};

// ---------------- prep: pack W + colstats partials + zero counters ----------------
__global__ __launch_bounds__(256) void prep_kernel(Params p) {
    const int y = blockIdx.y, bx = blockIdx.x, tid = threadIdx.x;

    if (y == 6) {
        if (bx < 64) {          // colstats partials: 64 blocks x 16 rows, plain stores
            const int d = tid, r0 = bx * 16;
            float s = 0.f, s2 = 0.f;
            #pragma unroll
            for (int r = 0; r < 16; ++r) {
                float v = p.b[(r0 + r) * DIM + d];
                s += v; s2 = fmaf(v, v, s2);
            }
            p.part_s[bx * 256 + d] = s;
            p.part_s2[bx * 256 + d] = s2;
        } else if (bx == 64) {  // zero counters + acc + done (3072 floats)
            #pragma unroll
            for (int k = 0; k < 12; ++k) p.zbase[tid + k * 256] = 0.f;
        }
        return;
    }
    __shared__ float T[32][33];
    const float* src = p.w[y];
    half_t* dst = p.wt[y];
    const int K = (y < 2) ? DIM : HID;
    const int N = (y < 4) ? HID : DIM;
    const int C = K >> 5;
    const int tilesN = N >> 5;
    if (bx >= C * tilesN) return;
    const int tk = bx / tilesN, tn = bx % tilesN;

    {
        const int r = tid >> 3, c4 = (tid & 7) * 4;
        float4 v = *(const float4*)&src[(tk * 32 + r) * N + tn * 32 + c4];
        T[r][c4 + 0] = v.x; T[r][c4 + 1] = v.y; T[r][c4 + 2] = v.z; T[r][c4 + 3] = v.w;
    }
    __syncthreads();
    const int which = tid >> 7;
    const int lane64 = (tid >> 1) & 63;
    const int epart = tid & 1;
    const int hi = lane64 >> 5, lr = lane64 & 31;
    const int rbase = which * 16 + hi * 8 + epart * 4;
    half4v h;
    h[0] = (half_t)T[rbase + 0][lr];
    h[1] = (half_t)T[rbase + 1][lr];
    h[2] = (half_t)T[rbase + 2][lr];
    h[3] = (half_t)T[rbase + 3][lr];
    *(half4v*)&dst[((tn * C + tk) * 2 + which) * 512 + lane64 * 8 + epart * 4] = h;
}

// ---------------- flag sync: WAVE-level publish (new), block-level wait ----------
__device__ __forceinline__ void flag_add_wave(unsigned* c) {
    asm volatile("s_waitcnt vmcnt(0)" ::: "memory");   // this wave's stores drained
    if ((threadIdx.x & 63) == 0)
        __hip_atomic_fetch_add(c, 1u, __ATOMIC_RELAXED, __HIP_MEMORY_SCOPE_AGENT);
}
__device__ __forceinline__ void flag_wait(unsigned* c, unsigned tgt) {
    if (threadIdx.x == 0) {
        while (__hip_atomic_load(c, __ATOMIC_RELAXED, __HIP_MEMORY_SCOPE_AGENT) < tgt)
            __builtin_amdgcn_s_sleep(1);
    }
    __syncthreads();
    asm volatile("" ::: "memory");
}

// ---------------- MFMA over KC chunks, first PRE W-chunks preloaded in regs ----
template <int KC, int PRE>
__device__ __forceinline__ f32x16 mma_pre(const half_t* __restrict__ Ap0,
                                          const half_t* __restrict__ Wp,
                                          const half8v (*wpre)[2], const int lane) {
    const int lr = lane & 31, hi = lane >> 5;
    const int sa = (lr >> 3) & 3;
    const int aoff0 = lr * 40 + ((hi ^ sa) * 8);
    const int aoff1 = lr * 40 + (((hi + 2) ^ sa) * 8);
    f32x16 acc;
    #pragma unroll
    for (int i = 0; i < 16; ++i) acc[i] = 0.f;
    #pragma unroll
    for (int c = 0; c < KC; ++c) {
        half8v av0 = *(const half8v*)(Ap0 + c * 1280 + aoff0);
        half8v av1 = *(const half8v*)(Ap0 + c * 1280 + aoff1);
        half8v bv0 = (c < PRE) ? wpre[c][0] : *(const half8v*)(Wp + c * 1024);
        half8v bv1 = (c < PRE) ? wpre[c][1] : *(const half8v*)(Wp + c * 1024 + 512);
        acc = __builtin_amdgcn_mfma_f32_32x32x16_f16(av0, bv0, acc, 0, 0, 0);
        acc = __builtin_amdgcn_mfma_f32_32x32x16_f16(av1, bv1, acc, 0, 0, 0);
    }
    return acc;
}

// ---------------- stage helpers (r13 proven) ----------------
__device__ __forceinline__ void stage_a(const float* __restrict__ a, half_t* XA,
                                        const int R0, const int tid) {
    const int r = tid >> 4, q = tid & 15;
    const float* src = &a[(R0 + r) * DIM + q * 16];
    float4 v0 = *(const float4*)(src);
    float4 v1 = *(const float4*)(src + 4);
    float4 v2 = *(const float4*)(src + 8);
    float4 v3 = *(const float4*)(src + 12);
    half8v h0, h1;
    h0[0] = (half_t)v0.x; h0[1] = (half_t)v0.y; h0[2] = (half_t)v0.z; h0[3] = (half_t)v0.w;
    h0[4] = (half_t)v1.x; h0[5] = (half_t)v1.y; h0[6] = (half_t)v1.z; h0[7] = (half_t)v1.w;
    h1[0] = (half_t)v2.x; h1[1] = (half_t)v2.y; h1[2] = (half_t)v2.z; h1[3] = (half_t)v2.w;
    h1[4] = (half_t)v3.x; h1[5] = (half_t)v3.y; h1[6] = (half_t)v3.z; h1[7] = (half_t)v3.w;
    const int c = q >> 1, kb0 = (q & 1) * 2, sr = (r >> 3) & 3;
    *(half8v*)&XA[c * 1280 + r * 40 + ((kb0 ^ sr) * 8)] = h0;
    *(half8v*)&XA[c * 1280 + r * 40 + (((kb0 + 1) ^ sr) * 8)] = h1;
}

__device__ __forceinline__ void stage_h(const half_t* __restrict__ src, half_t* XA,
                                        const int R0, const int tid) {
    const int r = tid >> 4, q = tid & 15;
    const half_t* sp = &src[(R0 + r) * HID + q * 32];
    half8v x0 = *(const half8v*)(sp);
    half8v x1 = *(const half8v*)(sp + 8);
    half8v x2 = *(const half8v*)(sp + 16);
    half8v x3 = *(const half8v*)(sp + 24);
    const int sr = (r >> 3) & 3;
    half_t* d = &XA[q * 1280 + r * 40];
    *(half8v*)&d[(0 ^ sr) * 8] = x0;
    *(half8v*)&d[(1 ^ sr) * 8] = x1;
    *(half8v*)&d[(2 ^ sr) * 8] = x2;
    *(half8v*)&d[(3 ^ sr) * 8] = x3;
}

#define OFF_REDH  24576
#define OFF_EB    41024
#define OFF_BSUM  43072

// ---------------- reduce + wide epilogue (r15 proven) ----------------
__device__ __forceinline__ void reduce2_wide(f32x16 acc, char* smem, int tl, int kh,
                                             int lane, int tid,
                                             const float* __restrict__ bias, int colbase,
                                             unsigned short* __restrict__ dstG,
                                             int R0, bool relu) {
    float* redf = (float*)smem;
    half_t* redh = (half_t*)(smem + OFF_REDH);
    __syncthreads();                    // XA reads complete
    if (kh) {
        #pragma unroll
        for (int i = 0; i < 16; ++i) redf[tl * 1024 + i * 64 + lane] = acc[i];
    }
    __syncthreads();
    if (!kh) {
        const int lr = lane & 31, hi = lane >> 5;
        const int coll = tl * 32 + lr;
        const float bv = bias[colbase + coll];
        #pragma unroll
        for (int i = 0; i < 16; ++i) {
            float v = acc[i] + redf[tl * 1024 + i * 64 + lane] + bv;
            if (relu) v = fmaxf(v, 0.f);
            const int row = (i & 3) + 8 * (i >> 2) + 4 * hi;
            redh[row * 136 + coll] = (half_t)v;
        }
    }
    __syncthreads();
    {
        const int row = tid >> 4, c8 = (tid & 15) * 8;
        const unsigned long long* sp = (const unsigned long long*)&redh[row * 136 + c8];
        unsigned long long v0 = sp[0], v1 = sp[1];
        unsigned long long* dp = (unsigned long long*)&dstG[(R0 + row) * HID + colbase + c8];
        __hip_atomic_store(dp, v0, __ATOMIC_RELAXED, __HIP_MEMORY_SCOPE_AGENT);
        __hip_atomic_store(dp + 1, v1, __ATOMIC_RELAXED, __HIP_MEMORY_SCOPE_AGENT);
    }
}

__device__ __forceinline__ void reduce4_wide(f32x16 acc, char* smem, int tl, int kq,
                                             int lane, int tid,
                                             const float* __restrict__ bias, int colbase,
                                             unsigned short* __restrict__ dstG,
                                             int R0) {
    float* redf = (float*)smem;
    half_t* redh = (half_t*)(smem + OFF_REDH);
    __syncthreads();
    if (kq) {
        #pragma unroll
        for (int i = 0; i < 16; ++i)
            redf[(tl * 3 + kq - 1) * 1024 + i * 64 + lane] = acc[i];
    }
    __syncthreads();
    if (!kq) {
        const int lr = lane & 31, hi = lane >> 5;
        const int coll = tl * 32 + lr;
        const float bv = bias[colbase + coll];
        #pragma unroll
        for (int i = 0; i < 16; ++i) {
            float v = acc[i] + bv
                    + redf[(tl * 3 + 0) * 1024 + i * 64 + lane]
                    + redf[(tl * 3 + 1) * 1024 + i * 64 + lane]
                    + redf[(tl * 3 + 2) * 1024 + i * 64 + lane];
            const int row = (i & 3) + 8 * (i >> 2) + 4 * hi;
            redh[row * 72 + coll] = (half_t)v;
        }
    }
    __syncthreads();
    {
        const int row = tid >> 4, c4 = (tid & 15) * 4;
        unsigned long long v0 = *(const unsigned long long*)&redh[row * 72 + c4];
        unsigned long long* dp = (unsigned long long*)&dstG[(R0 + row) * DIM + colbase + c4];
        __hip_atomic_store(dp, v0, __ATOMIC_RELAXED, __HIP_MEMORY_SCOPE_AGENT);
    }
}

// ---------------- main: 256 blocks = 2 nets x 32 rowgroups x 4 col-slices ----
__global__ void __launch_bounds__(512) main_kernel(Params p) {
    __shared__ alignas(16) char smem[43136];
    half_t* XA = (half_t*)smem;                 // [16][32][40] f16 (40960 B)
    float* ebL  = (float*)(smem + OFF_EB);      // [256]
    float* eb2L = ebL + 256;                    // [256]
    float* bsum = (float*)(smem + OFF_BSUM);

    const int bid = blockIdx.x, tid = threadIdx.x;
    const int net = bid & 1, g = (bid >> 1) & 31, s = bid >> 6;
    const int R0 = g * 32;
    const int w = tid >> 6, lane = tid & 63;

    half8v wpre[4][2];

    // ---- L0: a @ w[net] cols [s*128,+128) -> g_h1 ----
    stage_a(p.a, XA, R0, tid);
    __syncthreads();
    {
        const int tl = w >> 1, kh = w & 1;
        const half_t* Wp = p.wt[net] + ((s * 4 + tl) * 8 + kh * 4) * 1024 + lane * 8;
        f32x16 acc = mma_pre<4, 0>(XA + kh * 4 * 1280, Wp, nullptr, lane);
        reduce2_wide(acc, smem, tl, kh, lane, tid, p.bias[net], s * 128,
                     (unsigned short*)p.g_h1[net], R0, true);
    }
    flag_add_wave(p.c1 + (net * 32 + g) * CTR);

    // ---- L1: preload W before wait; h1 @ w[2+net] cols [s*128,+128) ----
    const int tl2 = w >> 1, kh2 = w & 1;
    const half_t* WpL1 = p.wt[2 + net] + ((s * 4 + tl2) * 16 + kh2 * 8) * 1024 + lane * 8;
    #pragma unroll
    for (int c = 0; c < 4; ++c) {
        wpre[c][0] = *(const half8v*)(WpL1 + c * 1024);
        wpre[c][1] = *(const half8v*)(WpL1 + c * 1024 + 512);
    }
    flag_wait(p.c1 + (net * 32 + g) * CTR, 32);
    stage_h(p.g_h1[net], XA, R0, tid);
    __syncthreads();
    {
        f32x16 acc = mma_pre<8, 4>(XA + kh2 * 8 * 1280, WpL1, wpre, lane);
        reduce2_wide(acc, smem, tl2, kh2, lane, tid, p.bias[2 + net], s * 128,
                     (unsigned short*)p.g_h2[net], R0, true);
    }
    flag_add_wave(p.c2 + (net * 32 + g) * CTR);

    // ---- L2: preload W before wait; h2 @ w[4+net] cols [s*64,+64) ----
    const int tl3 = w >> 2, kq3 = w & 3;
    const half_t* WpL2 = p.wt[4 + net] + ((s * 2 + tl3) * 16 + kq3 * 4) * 1024 + lane * 8;
    #pragma unroll
    for (int c = 0; c < 4; ++c) {
        wpre[c][0] = *(const half8v*)(WpL2 + c * 1024);
        wpre[c][1] = *(const half8v*)(WpL2 + c * 1024 + 512);
    }
    flag_wait(p.c2 + (net * 32 + g) * CTR, 32);
    stage_h(p.g_h2[net], XA, R0, tid);
    __syncthreads();
    {
        f32x16 acc = mma_pre<4, 4>(XA + kq3 * 4 * 1280, WpL2, wpre, lane);
        reduce4_wide(acc, smem, tl3, kq3, lane, tid, p.bias[4 + net], s * 64,
                     net ? p.g_lv : p.g_mu, R0);
    }
    flag_add_wave(p.c3 + g * CTR);

    if (net == 0) return;

    // ---- loss (net==1): colstats reduce in poll shadow, then 8 rows/block ----
    if (tid == 0) *bsum = 0.f;
    {
        const int which = tid >> 8, d = tid & 255;
        const float* P = which ? p.part_s2 : p.part_s;
        float ssum = 0.f;
        #pragma unroll 8
        for (int j = 0; j < 64; ++j) ssum += P[j * 256 + d];
        (which ? eb2L : ebL)[d] = ssum * (1.0f / (float)N_ROWS);
    }
    flag_wait(p.c3 + g * CTR, 64);          // syncthreads inside publishes ebL

    const int i = R0 + s * 8 + w;
    const int d0 = lane * 4;
    const half_t* muP = (const half_t*)p.g_mu;
    const half_t* lvP = (const half_t*)p.g_lv;
    half4v mh = *(const half4v*)&muP[i * DIM + d0];
    half4v lh = *(const half4v*)&lvP[i * DIM + d0];
    float4 ebf = *(const float4*)&ebL[d0];
    float4 eb2f = *(const float4*)&eb2L[d0];
    float m4[4] = {(float)mh[0], (float)mh[1], (float)mh[2], (float)mh[3]};
    float l4[4] = {(float)lh[0], (float)lh[1], (float)lh[2], (float)lh[3]};
    float eb[4] = {ebf.x, ebf.y, ebf.z, ebf.w};
    float eb2[4] = {eb2f.x, eb2f.y, eb2f.z, eb2f.w};

    float ss = 0.f;
    #pragma unroll
    for (int t = 0; t < 4; ++t) ss = fmaf(m4[t], m4[t], ss);
    #pragma unroll
    for (int o = 32; o > 0; o >>= 1) ss += __shfl_xor(ss, o, 64);
    const float inv_norm = 1.f / fmaxf(sqrtf(ss), 1e-12f);

    float wacc = 0.f;
    #pragma unroll
    for (int t = 0; t < 4; ++t) {
        float mu = m4[t] * inv_norm;
        float lv = tanhf(l4[t]);
        float iv = expf(-lv);
        float diff2 = fmaf(mu, mu, fmaf(-2.f * mu, eb[t], eb2[t]));
        wacc += fmaf(diff2, iv, lv);
    }
    #pragma unroll
    for (int o = 32; o > 0; o >>= 1) wacc += __shfl_xor(wacc, o, 64);
    if (lane == 0) atomicAdd(bsum, wacc);
    __syncthreads();
    if (tid == 0) {
        atomicAdd(p.acc, *bsum);
        asm volatile("s_waitcnt vmcnt(0)" ::: "memory");
        unsigned prev = __hip_atomic_fetch_add(p.done, 1u, __ATOMIC_RELAXED,
                                               __HIP_MEMORY_SCOPE_AGENT);
        if (prev == 127u) {
            float v = __hip_atomic_load(p.acc, __ATOMIC_RELAXED, __HIP_MEMORY_SCOPE_AGENT);
            p.out[0] = v * (1.0f / (float)N_ROWS);
        }
    }
}

extern "C" void kernel_launch(void* const* d_in, const int* in_sizes, int n_in,
                              void* d_out, int out_size, void* d_ws, size_t ws_size,
                              hipStream_t stream) {
    Params p;
    p.a = (const float*)d_in[0];
    p.b = (const float*)d_in[1];
    p.w[0] = (const float*)d_in[2];  p.bias[0] = (const float*)d_in[3];   // mu L0
    p.w[2] = (const float*)d_in[4];  p.bias[2] = (const float*)d_in[5];   // mu L1
    p.w[4] = (const float*)d_in[6];  p.bias[4] = (const float*)d_in[7];   // mu L2
    p.w[1] = (const float*)d_in[8];  p.bias[1] = (const float*)d_in[9];   // lv L0
    p.w[3] = (const float*)d_in[10]; p.bias[3] = (const float*)d_in[11];  // lv L1
    p.w[5] = (const float*)d_in[12]; p.bias[5] = (const float*)d_in[13];  // lv L2

    float* f = (float*)d_ws;
    p.c1    = (unsigned*)f;                 // 64 x CTR = f[0..1023]
    p.c2    = (unsigned*)(f + 1024);        // 64 x CTR = f[1024..2047]
    p.c3    = (unsigned*)(f + 2048);        // 32 x CTR = f[2048..2559]
    p.acc   = f + 2560;
    p.done  = (unsigned*)(f + 2576);
    p.zbase = f;                            // prep zeroes f[0..3071]
    p.part_s  = f + 4096;                   // [64][256]
    p.part_s2 = f + 20480;                  // [64][256]
    p.g_mu = (unsigned short*)(f + 36864);  // 1024*256 u16
    p.g_lv = p.g_mu + N_ROWS * DIM;
    half_t* hb = (half_t*)(p.g_lv + N_ROWS * DIM);
    p.g_h1[0] = hb;  hb += N_ROWS * HID;
    p.g_h1[1] = hb;  hb += N_ROWS * HID;
    p.g_h2[0] = hb;  hb += N_ROWS * HID;
    p.g_h2[1] = hb;  hb += N_ROWS * HID;
    p.wt[0] = hb;  hb += HID * DIM;
    p.wt[1] = hb;  hb += HID * DIM;
    p.wt[2] = hb;  hb += HID * HID;
    p.wt[3] = hb;  hb += HID * HID;
    p.wt[4] = hb;  hb += DIM * HID;
    p.wt[5] = hb;  hb += DIM * HID;
    p.out = (float*)d_out;

    prep_kernel<<<dim3(256, 7), 256, 0, stream>>>(p);
    main_kernel<<<256, 512, 0, stream>>>(p);
}